// Round 3
// baseline (130.369 us; speedup 1.0000x reference)
//
#include <hip/hip_runtime.h>

#if defined(__has_builtin)
#if __has_builtin(__builtin_amdgcn_exp2f)
#define EXP2F(x) __builtin_amdgcn_exp2f(x)
#endif
#endif
#ifndef EXP2F
#define EXP2F(x) exp2f(x)
#endif

#define BLOCK 256
#define QPT 4       // queries per thread (2 packed float2 pairs)
#define TILE 512    // train points staged in LDS per iteration
#define MAX_SEGS 128

typedef float v2f __attribute__((ext_vector_type(2)));

// scores = -0.5*((q-x)*w)^2 ; fold sqrt(0.5*log2(e)) into w so exp2 applies
// directly: exp2(-(t*t)) with t = (q-x)*w*K  ==  e^{-0.5*((q-x)w)^2}
// Staging precomputes a = w*K and nb = -x*w*K so t = fma(q, a, nb).
#define KFOLD 0.8493218f  // sqrt(0.5 * log2(e))

__global__ __launch_bounds__(BLOCK) void nw_partial(
    const float* __restrict__ q, const float* __restrict__ xt,
    const float* __restrict__ yt, const float* __restrict__ w,
    float2* __restrict__ partial, int n_q, int n_t, int segs)
{
    __shared__ float4 tile[TILE];
    const int seg = blockIdx.x;
    const int tid = threadIdx.x;
    const int qbase = blockIdx.y * (BLOCK * QPT) + tid;

    // q2[p] holds queries {qbase + 2p*BLOCK, qbase + (2p+1)*BLOCK}
    v2f q2[QPT / 2];
    v2f acc[QPT];  // acc[i] = {num_i, den_i}
#pragma unroll
    for (int i = 0; i < QPT; ++i) {
        int qi = qbase + i * BLOCK;
        float qv = (qi < n_q) ? q[qi] : 0.f;
        if (i & 1) q2[i >> 1].y = qv; else q2[i >> 1].x = qv;
        acc[i] = (v2f){0.f, 0.f};
    }

    const int seg_len = (n_t + segs - 1) / segs;
    const int s0 = seg * seg_len;
    const int s1 = min(s0 + seg_len, n_t);

    for (int base = s0; base < s1; base += TILE) {
        const int cnt = min(TILE, s1 - base);
        __syncthreads();
        for (int j = tid; j < cnt; j += BLOCK) {
            float a = w[base + j] * KFOLD;
            tile[j] = make_float4(a, -xt[base + j] * a, yt[base + j], 0.f);
        }
        __syncthreads();
#pragma unroll 8
        for (int j = 0; j < cnt; ++j) {
            float4 v = tile[j];                 // {a, nb, y, -}
            v2f a2  = (v2f){v.x, v.x};
            v2f nb2 = (v2f){v.y, v.y};
            v2f ym  = (v2f){v.z, 1.0f};
#pragma unroll
            for (int p = 0; p < QPT / 2; ++p) {
                v2f t = __builtin_elementwise_fma(q2[p], a2, nb2);
                v2f s = -(t * t);               // v_pk_mul_f32 + neg
                float e0 = EXP2F(s.x);
                float e1 = EXP2F(s.y);
                acc[2 * p]     = __builtin_elementwise_fma((v2f){e0, e0}, ym,
                                                           acc[2 * p]);
                acc[2 * p + 1] = __builtin_elementwise_fma((v2f){e1, e1}, ym,
                                                           acc[2 * p + 1]);
            }
        }
    }

#pragma unroll
    for (int i = 0; i < QPT; ++i) {
        int qi = qbase + i * BLOCK;
        if (qi < n_q) partial[seg * n_q + qi] = make_float2(acc[i].x, acc[i].y);
    }
}

__global__ __launch_bounds__(BLOCK) void nw_reduce(
    const float2* __restrict__ partial, float* __restrict__ out,
    int n_q, int segs)
{
    int qi = blockIdx.x * blockDim.x + threadIdx.x;
    if (qi >= n_q) return;
    float num = 0.f, den = 0.f;
    for (int s = 0; s < segs; ++s) {
        float2 p = partial[s * n_q + qi];
        num += p.x;
        den += p.y;
    }
    out[qi] = num / den;
}

extern "C" void kernel_launch(void* const* d_in, const int* in_sizes, int n_in,
                              void* d_out, int out_size, void* d_ws, size_t ws_size,
                              hipStream_t stream) {
    const float* q  = (const float*)d_in[0];
    const float* xt = (const float*)d_in[1];
    const float* yt = (const float*)d_in[2];
    const float* w  = (const float*)d_in[3];
    const int n_q = in_sizes[0];
    const int n_t = in_sizes[1];

    // split-K segments, clamped so partials fit in the workspace
    int segs = MAX_SEGS;
    size_t need = (size_t)segs * (size_t)n_q * sizeof(float2);
    if (need > ws_size) {
        segs = (int)(ws_size / ((size_t)n_q * sizeof(float2)));
        if (segs < 1) segs = 1;
    }

    float2* partial = (float2*)d_ws;
    dim3 grid(segs, (n_q + BLOCK * QPT - 1) / (BLOCK * QPT));
    nw_partial<<<grid, BLOCK, 0, stream>>>(q, xt, yt, w, partial, n_q, n_t, segs);
    nw_reduce<<<(n_q + BLOCK - 1) / BLOCK, BLOCK, 0, stream>>>(partial,
                                                              (float*)d_out,
                                                              n_q, segs);
}

// Round 4
// 107.415 us; speedup vs baseline: 1.2137x; 1.2137x over previous
//
#include <hip/hip_runtime.h>

#if defined(__has_builtin)
#if __has_builtin(__builtin_amdgcn_exp2f)
#define EXP2F(x) __builtin_amdgcn_exp2f(x)
#endif
#endif
#ifndef EXP2F
#define EXP2F(x) exp2f(x)
#endif

#define BLOCK 256
#define QPT 8        // queries per thread (4 packed float2 pairs)
#define TILE 512     // train points staged in LDS per iteration
#define MAX_SEGS 128
#define RSPLIT 4     // seg-parallelism per query in the reduce

typedef float v2f __attribute__((ext_vector_type(2)));

// scores = -0.5*((q-x)*w)^2 ; fold sqrt(0.5*log2(e)) into w so exp2 applies
// directly: exp2(-(t*t)) with t = (q-x)*w*K  ==  e^{-0.5*((q-x)w)^2}
// Staging precomputes a = w*K and nb = -x*w*K so t = fma(q, a, nb).
#define KFOLD 0.8493218f  // sqrt(0.5 * log2(e))

__global__ __launch_bounds__(BLOCK) void nw_partial(
    const float* __restrict__ q, const float* __restrict__ xt,
    const float* __restrict__ yt, const float* __restrict__ w,
    float2* __restrict__ partial, int n_q, int n_t, int segs)
{
    __shared__ float4 tile[TILE];
    const int seg = blockIdx.x;
    const int tid = threadIdx.x;
    const int qbase = blockIdx.y * (BLOCK * QPT) + tid;

    // q2[p] holds queries {qbase + 2p*BLOCK, qbase + (2p+1)*BLOCK}
    v2f q2[QPT / 2];
    v2f acc[QPT];  // acc[i] = {num_i, den_i}
#pragma unroll
    for (int i = 0; i < QPT; ++i) {
        int qi = qbase + i * BLOCK;
        float qv = (qi < n_q) ? q[qi] : 0.f;
        if (i & 1) q2[i >> 1].y = qv; else q2[i >> 1].x = qv;
        acc[i] = (v2f){0.f, 0.f};
    }

    const int seg_len = (n_t + segs - 1) / segs;
    const int s0 = seg * seg_len;
    const int s1 = min(s0 + seg_len, n_t);

    for (int base = s0; base < s1; base += TILE) {
        const int cnt = min(TILE, s1 - base);
        __syncthreads();
        for (int j = tid; j < cnt; j += BLOCK) {
            float a = w[base + j] * KFOLD;
            tile[j] = make_float4(a, -xt[base + j] * a, yt[base + j], 0.f);
        }
        __syncthreads();
#pragma unroll 2
        for (int j = 0; j < cnt; ++j) {
            float4 v = tile[j];                 // {a, nb, y, -}
            v2f a2  = (v2f){v.x, v.x};
            v2f nb2 = (v2f){v.y, v.y};
            v2f ym  = (v2f){v.z, 1.0f};
#pragma unroll
            for (int p = 0; p < QPT / 2; ++p) {
                v2f t = __builtin_elementwise_fma(q2[p], a2, nb2);
                v2f s = -(t * t);               // v_pk_mul_f32 (neg on src)
                float e0 = EXP2F(s.x);
                float e1 = EXP2F(s.y);
                acc[2 * p]     = __builtin_elementwise_fma((v2f){e0, e0}, ym,
                                                           acc[2 * p]);
                acc[2 * p + 1] = __builtin_elementwise_fma((v2f){e1, e1}, ym,
                                                           acc[2 * p + 1]);
            }
        }
    }

#pragma unroll
    for (int i = 0; i < QPT; ++i) {
        int qi = qbase + i * BLOCK;
        if (qi < n_q) partial[seg * n_q + qi] = make_float2(acc[i].x, acc[i].y);
    }
}

// Block handles 64 queries; 4 threads per query split the segs dimension.
// Lane layout: qi_local = tid & 63 within each 64-thread group? No — use
// c = tid / 64 (wave index), qi_local = tid % 64, so every wave's 64 lanes
// read 64 consecutive qi -> fully coalesced 512B per iteration.
__global__ __launch_bounds__(BLOCK) void nw_reduce(
    const float2* __restrict__ partial, float* __restrict__ out,
    int n_q, int segs)
{
    __shared__ float2 red[RSPLIT][64];
    const int tid = threadIdx.x;
    const int c = tid >> 6;          // 0..3 (seg chunk = wave index)
    const int ql = tid & 63;         // query within block
    const int qi = blockIdx.x * 64 + ql;

    float num = 0.f, den = 0.f;
    if (qi < n_q) {
        for (int s = c; s < segs; s += RSPLIT) {
            float2 p = partial[(size_t)s * n_q + qi];
            num += p.x;
            den += p.y;
        }
    }
    red[c][ql] = make_float2(num, den);
    __syncthreads();
    if (c == 0 && qi < n_q) {
        float2 r1 = red[1][ql], r2 = red[2][ql], r3 = red[3][ql];
        num += r1.x + r2.x + r3.x;
        den += r1.y + r2.y + r3.y;
        out[qi] = num / den;
    }
}

extern "C" void kernel_launch(void* const* d_in, const int* in_sizes, int n_in,
                              void* d_out, int out_size, void* d_ws, size_t ws_size,
                              hipStream_t stream) {
    const float* q  = (const float*)d_in[0];
    const float* xt = (const float*)d_in[1];
    const float* yt = (const float*)d_in[2];
    const float* w  = (const float*)d_in[3];
    const int n_q = in_sizes[0];
    const int n_t = in_sizes[1];

    // split-K segments, clamped so partials fit in the workspace
    int segs = MAX_SEGS;
    size_t need = (size_t)segs * (size_t)n_q * sizeof(float2);
    if (need > ws_size) {
        segs = (int)(ws_size / ((size_t)n_q * sizeof(float2)));
        if (segs < 1) segs = 1;
    }

    float2* partial = (float2*)d_ws;
    dim3 grid(segs, (n_q + BLOCK * QPT - 1) / (BLOCK * QPT));
    nw_partial<<<grid, BLOCK, 0, stream>>>(q, xt, yt, w, partial, n_q, n_t, segs);
    nw_reduce<<<(n_q + 63) / 64, BLOCK, 0, stream>>>(partial, (float*)d_out,
                                                     n_q, segs);
}